// Round 3
// baseline (1389.433 us; speedup 1.0000x reference)
//
#include <hip/hip_runtime.h>
#include <math.h>

#define N 8192
#define C 128
#define NC 256
#define KNN 5

#define TI 64
#define TJ 64
#define JSPLIT 8
#define JTILES ((N / JSPLIT) / TJ)   // 16
#define LDSROW 68                    // floats per LDS row
#define SQRT_C 11.313708498984761    // sqrt(128)
#define BROWS 16                     // rows per block in parent_stream

static __device__ __forceinline__ unsigned rotl32(unsigned x, unsigned r) {
    return (x << r) | (x >> (32u - r));
}

// ---------------------------------------------------------------------------
__global__ void init_kernel(unsigned long long* d2max) { *d2max = 0ull; }

// ---------------------------------------------------------------------------
// sq[i] = sum_c (double)x[i][c]^2
// ---------------------------------------------------------------------------
__global__ void sq_kernel(const float* __restrict__ X, double* __restrict__ sq) {
    int wave = (blockIdx.x * blockDim.x + threadIdx.x) >> 6;
    int lane = threadIdx.x & 63;
    if (wave >= N) return;
    double v0 = (double)X[wave * C + lane];
    double v1 = (double)X[wave * C + 64 + lane];
    double s = v0 * v0 + v1 * v1;
    #pragma unroll
    for (int off = 32; off > 0; off >>= 1) s += __shfl_down(s, off, 64);
    if (lane == 0) sq[wave] = s;
}

// ---------------------------------------------------------------------------
// JAX threefry2x32: uniform(key(1), (1,8192))
// ---------------------------------------------------------------------------
__global__ void noise_kernel(float* __restrict__ noise) {
    int j = blockIdx.x * blockDim.x + threadIdx.x;
    if (j >= N / 2) return;
    const unsigned ks0 = 0u, ks1 = 1u;
    const unsigned ks2 = 0x1BD11BDAu ^ ks0 ^ ks1;
    unsigned x0 = (unsigned)j + ks0;
    unsigned x1 = (unsigned)(j + N / 2) + ks1;
    const unsigned rotA[4] = {13u, 15u, 26u, 6u};
    const unsigned rotB[4] = {17u, 29u, 16u, 24u};
    #pragma unroll
    for (int r = 0; r < 4; r++) { x0 += x1; x1 = rotl32(x1, rotA[r]); x1 ^= x0; }
    x0 += ks1; x1 += ks2 + 1u;
    #pragma unroll
    for (int r = 0; r < 4; r++) { x0 += x1; x1 = rotl32(x1, rotB[r]); x1 ^= x0; }
    x0 += ks2; x1 += ks0 + 2u;
    #pragma unroll
    for (int r = 0; r < 4; r++) { x0 += x1; x1 = rotl32(x1, rotA[r]); x1 ^= x0; }
    x0 += ks0; x1 += ks1 + 3u;
    #pragma unroll
    for (int r = 0; r < 4; r++) { x0 += x1; x1 = rotl32(x1, rotB[r]); x1 ^= x0; }
    x0 += ks1; x1 += ks2 + 4u;
    #pragma unroll
    for (int r = 0; r < 4; r++) { x0 += x1; x1 = rotl32(x1, rotA[r]); x1 ^= x0; }
    x0 += ks2; x1 += ks0 + 5u;
    unsigned b0 = (x0 >> 9) | 0x3f800000u;
    unsigned b1 = (x1 >> 9) | 0x3f800000u;
    noise[j]         = __uint_as_float(b0) - 1.0f;
    noise[j + N / 2] = __uint_as_float(b1) - 1.0f;
}

// ---------------------------------------------------------------------------
// Pass A: d2 GEMM + per-row top-5 + global max. Optionally stores d2 (f64).
// Register-prefetch double-buffered B staging.
// ---------------------------------------------------------------------------
template <bool STORE>
__launch_bounds__(256, 2)
__global__ void density_partial_kernel(const float* __restrict__ X,
                                       const double* __restrict__ sq,
                                       double* __restrict__ top5part,  // [JSPLIT][N][5]
                                       unsigned long long* __restrict__ d2max_p,
                                       double* __restrict__ d2out)     // [N][N] or null
{
    __shared__ __align__(16) float S[2 * C * LDSROW];
    __shared__ double Sqj[TJ];
    __shared__ double wmax[4];
    float* As = S;
    float* Bs = S + C * LDSROW;

    const int t  = threadIdx.x;
    const int tx = t & 15;
    const int ty = t >> 4;
    const int i0 = (blockIdx.x & 127) * TI;
    const int js = blockIdx.x >> 7;
    const int jbase = js * (N / JSPLIT);

    const float4* X4 = (const float4*)X;

    // stage A tile once: [c][i] transposed
    #pragma unroll
    for (int q = 0; q < 8; q++) {
        int flat = t + 256 * q;
        int row = flat >> 5, c4 = flat & 31;
        float4 v = X4[(size_t)(i0 + row) * 32 + c4];
        float* dst = &As[(4 * c4) * LDSROW + row];
        dst[0 * LDSROW] = v.x; dst[1 * LDSROW] = v.y;
        dst[2 * LDSROW] = v.z; dst[3 * LDSROW] = v.w;
    }

    double sqa[4];
    #pragma unroll
    for (int r = 0; r < 4; r++) sqa[r] = sq[i0 + 4 * ty + r];

    double t5[4][KNN];
    #pragma unroll
    for (int r = 0; r < 4; r++)
        #pragma unroll
        for (int k = 0; k < KNN; k++) t5[r][k] = 1e300;
    double rowmax = 0.0;

    // prefetch j-tile 0 into registers
    float4 pre[8];
    double preSq = 0.0;
    #pragma unroll
    for (int q = 0; q < 8; q++) {
        int flat = t + 256 * q;
        int row = flat >> 5, c4 = flat & 31;
        pre[q] = X4[(size_t)(jbase + row) * 32 + c4];
    }
    if (t < TJ) preSq = sq[jbase + t];

    for (int jt = 0; jt < JTILES; jt++) {
        int j0 = jbase + jt * TJ;
        __syncthreads();   // previous compute done; Bs free
        #pragma unroll
        for (int q = 0; q < 8; q++) {
            int flat = t + 256 * q;
            int row = flat >> 5, c4 = flat & 31;
            float* dst = &Bs[(4 * c4) * LDSROW + row];
            dst[0 * LDSROW] = pre[q].x; dst[1 * LDSROW] = pre[q].y;
            dst[2 * LDSROW] = pre[q].z; dst[3 * LDSROW] = pre[q].w;
        }
        if (t < TJ) Sqj[t] = preSq;
        __syncthreads();
        if (jt + 1 < JTILES) {   // issue next tile's loads; drained next iter
            int jn = j0 + TJ;
            #pragma unroll
            for (int q = 0; q < 8; q++) {
                int flat = t + 256 * q;
                int row = flat >> 5, c4 = flat & 31;
                pre[q] = X4[(size_t)(jn + row) * 32 + c4];
            }
            if (t < TJ) preSq = sq[jn + t];
        }

        double acc[4][4];
        #pragma unroll
        for (int r = 0; r < 4; r++)
            #pragma unroll
            for (int s = 0; s < 4; s++) acc[r][s] = 0.0;

        #pragma unroll 4
        for (int c = 0; c < C; c++) {
            float4 af = *(const float4*)&As[c * LDSROW + 4 * ty];
            float4 bf = *(const float4*)&Bs[c * LDSROW + 4 * tx];
            double a0 = af.x, a1 = af.y, a2 = af.z, a3 = af.w;
            double b0 = bf.x, b1 = bf.y, b2 = bf.z, b3 = bf.w;
            acc[0][0] += a0 * b0; acc[0][1] += a0 * b1; acc[0][2] += a0 * b2; acc[0][3] += a0 * b3;
            acc[1][0] += a1 * b0; acc[1][1] += a1 * b1; acc[1][2] += a1 * b2; acc[1][3] += a1 * b3;
            acc[2][0] += a2 * b0; acc[2][1] += a2 * b1; acc[2][2] += a2 * b2; acc[2][3] += a2 * b3;
            acc[3][0] += a3 * b0; acc[3][1] += a3 * b1; acc[3][2] += a3 * b2; acc[3][3] += a3 * b3;
        }

        #pragma unroll
        for (int r = 0; r < 4; r++) {
            double v[4];
            #pragma unroll
            for (int s = 0; s < 4; s++) {
                v[s] = sqa[r] + Sqj[4 * tx + s] - 2.0 * acc[r][s];
                rowmax = fmax(rowmax, v[s]);
                if (v[s] < t5[r][0]) {
                    t5[r][0] = v[s];
                    #pragma unroll
                    for (int k = 1; k < KNN; k++)
                        if (t5[r][k] > t5[r][0]) { double tmp = t5[r][0]; t5[r][0] = t5[r][k]; t5[r][k] = tmp; }
                }
            }
            if (STORE) {
                double* dst = &d2out[(size_t)(i0 + 4 * ty + r) * N + j0 + 4 * tx];
                double2 p0; p0.x = v[0]; p0.y = v[1];
                double2 p1; p1.x = v[2]; p1.y = v[3];
                *(double2*)dst = p0;
                *(double2*)(dst + 2) = p1;
            }
        }
    }

    double tmax = rowmax;
    #pragma unroll
    for (int off = 32; off > 0; off >>= 1) tmax = fmax(tmax, __shfl_down(tmax, off, 64));
    if ((t & 63) == 0) wmax[t >> 6] = tmax;

    __syncthreads();

    double* M = (double*)S;
    #pragma unroll
    for (int r = 0; r < 4; r++)
        #pragma unroll
        for (int k = 0; k < KNN; k++)
            M[(4 * ty + r) * 80 + tx * KNN + k] = t5[r][k];
    __syncthreads();

    if (t == 0) {
        double bm = fmax(fmax(wmax[0], wmax[1]), fmax(wmax[2], wmax[3]));
        bm = fmax(bm, 0.0);
        atomicMax(d2max_p, (unsigned long long)__double_as_longlong(bm));
    }
    if (t < TI) {
        double m5[KNN];
        #pragma unroll
        for (int k = 0; k < KNN; k++) m5[k] = 1e300;
        const double* row = &M[t * 80];
        for (int q = 0; q < 80; q++) {
            double v = row[q];
            if (v < m5[0]) {
                m5[0] = v;
                #pragma unroll
                for (int k = 1; k < KNN; k++)
                    if (m5[k] > m5[0]) { double tmp = m5[0]; m5[0] = m5[k]; m5[k] = tmp; }
            }
        }
        double* outp = &top5part[((size_t)js * N + (i0 + t)) * KNN];
        #pragma unroll
        for (int k = 0; k < KNN; k++) outp[k] = m5[k];
    }
}

// ---------------------------------------------------------------------------
__global__ void density_merge_kernel(const double* __restrict__ top5part,
                                     const float* __restrict__ noise,
                                     double* __restrict__ density)
{
    int i = blockIdx.x * blockDim.x + threadIdx.x;
    if (i >= N) return;
    double t5[KNN];
    #pragma unroll
    for (int k = 0; k < KNN; k++) t5[k] = 1e300;
    for (int js = 0; js < JSPLIT; js++) {
        const double* p = &top5part[((size_t)js * N + i) * KNN];
        #pragma unroll
        for (int k = 0; k < KNN; k++) {
            double v = p[k];
            if (v < t5[0]) {
                t5[0] = v;
                #pragma unroll
                for (int q = 1; q < KNN; q++)
                    if (t5[q] > t5[0]) { double tmp = t5[0]; t5[0] = t5[q]; t5[q] = tmp; }
            }
        }
    }
    for (int a = 1; a < KNN; a++) {
        double key = t5[a]; int b = a - 1;
        while (b >= 0 && t5[b] > key) { t5[b + 1] = t5[b]; b--; }
        t5[b + 1] = key;
    }
    double s2 = 0.0;
    #pragma unroll
    for (int k = 0; k < KNN; k++) {
        double z = t5[k] > 0.0 ? t5[k] : 0.0;
        double d = sqrt(z) / SQRT_C;
        s2 += d * d;
    }
    double m = s2 / 5.0;
    density[i] = exp(-m) + (double)(noise[i] * 1e-6f);
}

// ---------------------------------------------------------------------------
// Pass B fast path: stream stored d2, masked min per row, score direct.
// ---------------------------------------------------------------------------
__launch_bounds__(256)
__global__ void parent_stream_kernel(const double* __restrict__ d2,
                                     const double* __restrict__ density,
                                     const unsigned long long* __restrict__ d2max_p,
                                     double* __restrict__ score)
{
    const int t  = threadIdx.x;
    const int i0 = blockIdx.x * BROWS;

    double di[BROWS], dmin[BROWS];
    #pragma unroll
    for (int r = 0; r < BROWS; r++) { di[r] = density[i0 + r]; dmin[r] = 1e300; }

    for (int k = 0; k < N / 512; k++) {
        int j = 2 * (t + 256 * k);
        double2 dj = *(const double2*)&density[j];
        #pragma unroll
        for (int r = 0; r < BROWS; r++) {
            double2 v = *(const double2*)&d2[(size_t)(i0 + r) * N + j];
            if (dj.x > di[r]) dmin[r] = fmin(dmin[r], v.x);
            if (dj.y > di[r]) dmin[r] = fmin(dmin[r], v.y);
        }
    }

    __shared__ double red[4][BROWS];
    int lane = t & 63, w = t >> 6;
    #pragma unroll
    for (int r = 0; r < BROWS; r++) {
        double m = dmin[r];
        #pragma unroll
        for (int off = 32; off > 0; off >>= 1) m = fmin(m, __shfl_down(m, off, 64));
        if (lane == 0) red[w][r] = m;
    }
    __syncthreads();
    if (t < BROWS) {
        double m = fmin(fmin(red[0][t], red[1][t]), fmin(red[2][t], red[3][t]));
        double d2m = __longlong_as_double((long long)(*d2max_p));
        double distmax = sqrt(fmax(d2m, 0.0)) / SQRT_C;
        double dp = (m > 9.9e299) ? distmax : sqrt(fmax(m, 0.0)) / SQRT_C;
        score[i0 + t] = dp * di[t];
    }
}

// ---------------------------------------------------------------------------
// Pass B fallback (recompute) — unchanged from R2.
// ---------------------------------------------------------------------------
__launch_bounds__(256, 2)
__global__ void parent_partial_kernel(const float* __restrict__ X,
                                      const double* __restrict__ sq,
                                      const double* __restrict__ density,
                                      double* __restrict__ minpart)
{
    __shared__ __align__(16) float S[2 * C * LDSROW];
    __shared__ double Sqj[TJ];
    __shared__ double Dj[TJ];
    float* As = S;
    float* Bs = S + C * LDSROW;

    const int t  = threadIdx.x;
    const int tx = t & 15;
    const int ty = t >> 4;
    const int i0 = (blockIdx.x & 127) * TI;
    const int js = blockIdx.x >> 7;
    const int jbase = js * (N / JSPLIT);

    const float4* X4 = (const float4*)X;

    #pragma unroll
    for (int q = 0; q < 8; q++) {
        int flat = t + 256 * q;
        int row = flat >> 5, c4 = flat & 31;
        float4 v = X4[(size_t)(i0 + row) * 32 + c4];
        float* dst = &As[(4 * c4) * LDSROW + row];
        dst[0 * LDSROW] = v.x; dst[1 * LDSROW] = v.y;
        dst[2 * LDSROW] = v.z; dst[3 * LDSROW] = v.w;
    }

    double sqa[4], di[4], dmin[4];
    #pragma unroll
    for (int r = 0; r < 4; r++) {
        sqa[r] = sq[i0 + 4 * ty + r];
        di[r]  = density[i0 + 4 * ty + r];
        dmin[r] = 1e300;
    }

    for (int jt = 0; jt < JTILES; jt++) {
        int j0 = jbase + jt * TJ;
        __syncthreads();
        if (t < TJ) { Sqj[t] = sq[j0 + t]; Dj[t] = density[j0 + t]; }
        #pragma unroll
        for (int q = 0; q < 8; q++) {
            int flat = t + 256 * q;
            int row = flat >> 5, c4 = flat & 31;
            float4 v = X4[(size_t)(j0 + row) * 32 + c4];
            float* dst = &Bs[(4 * c4) * LDSROW + row];
            dst[0 * LDSROW] = v.x; dst[1 * LDSROW] = v.y;
            dst[2 * LDSROW] = v.z; dst[3 * LDSROW] = v.w;
        }
        __syncthreads();

        double acc[4][4];
        #pragma unroll
        for (int r = 0; r < 4; r++)
            #pragma unroll
            for (int s = 0; s < 4; s++) acc[r][s] = 0.0;

        #pragma unroll 4
        for (int c = 0; c < C; c++) {
            float4 af = *(const float4*)&As[c * LDSROW + 4 * ty];
            float4 bf = *(const float4*)&Bs[c * LDSROW + 4 * tx];
            double a0 = af.x, a1 = af.y, a2 = af.z, a3 = af.w;
            double b0 = bf.x, b1 = bf.y, b2 = bf.z, b3 = bf.w;
            acc[0][0] += a0 * b0; acc[0][1] += a0 * b1; acc[0][2] += a0 * b2; acc[0][3] += a0 * b3;
            acc[1][0] += a1 * b0; acc[1][1] += a1 * b1; acc[1][2] += a1 * b2; acc[1][3] += a1 * b3;
            acc[2][0] += a2 * b0; acc[2][1] += a2 * b1; acc[2][2] += a2 * b2; acc[2][3] += a2 * b3;
            acc[3][0] += a3 * b0; acc[3][1] += a3 * b1; acc[3][2] += a3 * b2; acc[3][3] += a3 * b3;
        }

        #pragma unroll
        for (int r = 0; r < 4; r++) {
            #pragma unroll
            for (int s = 0; s < 4; s++) {
                double v = sqa[r] + Sqj[4 * tx + s] - 2.0 * acc[r][s];
                if (Dj[4 * tx + s] > di[r]) dmin[r] = fmin(dmin[r], v);
            }
        }
    }

    __syncthreads();
    double* M = (double*)S;
    #pragma unroll
    for (int r = 0; r < 4; r++) M[(4 * ty + r) * 16 + tx] = dmin[r];
    __syncthreads();
    if (t < TI) {
        double m = 1e300;
        const double* row = &M[t * 16];
        #pragma unroll
        for (int q = 0; q < 16; q++) m = fmin(m, row[q]);
        minpart[(size_t)js * N + (i0 + t)] = m;
    }
}

__global__ void score_merge_kernel(const double* __restrict__ minpart,
                                   const double* __restrict__ density,
                                   const unsigned long long* __restrict__ d2max_p,
                                   double* __restrict__ score)
{
    int i = blockIdx.x * blockDim.x + threadIdx.x;
    if (i >= N) return;
    double dmin = 1e300;
    for (int js = 0; js < JSPLIT; js++) dmin = fmin(dmin, minpart[(size_t)js * N + i]);
    double d2m = __longlong_as_double((long long)(*d2max_p));
    double distmax = sqrt(fmax(d2m, 0.0)) / SQRT_C;
    double dp = (dmin > 9.9e299) ? distmax : sqrt(fmax(dmin, 0.0)) / SQRT_C;
    score[i] = dp * density[i];
}

// ---------------------------------------------------------------------------
// Stable descending rank; out[rank] = i.
// ---------------------------------------------------------------------------
__launch_bounds__(256)
__global__ void rank_kernel(const double* __restrict__ score, int* __restrict__ out)
{
    __shared__ double Ss[N];
    #pragma unroll
    for (int k = 0; k < N / 256; k++) {
        int idx = threadIdx.x + 256 * k;
        Ss[idx] = score[idx];
    }
    __syncthreads();
    int i = blockIdx.x * 256 + threadIdx.x;
    double si = Ss[i];
    int rank = 0;
    for (int j = 0; j < N; j++) {
        double sj = Ss[j];
        rank += (sj > si) || (sj == si && j < i);
    }
    if (rank < NC) out[rank] = i;
}

// ---------------------------------------------------------------------------
extern "C" void kernel_launch(void* const* d_in, const int* in_sizes, int n_in,
                              void* d_out, int out_size, void* d_ws, size_t ws_size,
                              hipStream_t stream) {
    const float* X = (const float*)d_in[0];
    int* out = (int*)d_out;

    double* ws      = (double*)d_ws;
    double* sq      = ws;                      // 8192
    double* density = ws + 8192;               // 8192
    double* score   = ws + 16384;              // 8192
    unsigned long long* d2max = (unsigned long long*)(ws + 24576);
    float*  noise   = (float*)(ws + 24584);    // 8192 floats
    double* top5part = ws + 28680;             // 327680
    double* minpart  = ws + 28680 + (size_t)JSPLIT * N * KNN;  // 65536

    const size_t base_need = 4ull * 1024 * 1024;
    const size_t d2_bytes  = (size_t)N * N * sizeof(double);   // 512 MiB
    const bool   big = ws_size >= base_need + d2_bytes;
    double* d2m = (double*)((char*)d_ws + base_need);

    init_kernel<<<1, 1, 0, stream>>>(d2max);
    sq_kernel<<<N / 4, 256, 0, stream>>>(X, sq);
    noise_kernel<<<(N / 2) / 256, 256, 0, stream>>>(noise);

    if (big) {
        density_partial_kernel<true><<<(N / TI) * JSPLIT, 256, 0, stream>>>(X, sq, top5part, d2max, d2m);
        density_merge_kernel<<<N / 256, 256, 0, stream>>>(top5part, noise, density);
        parent_stream_kernel<<<N / BROWS, 256, 0, stream>>>(d2m, density, d2max, score);
    } else {
        density_partial_kernel<false><<<(N / TI) * JSPLIT, 256, 0, stream>>>(X, sq, top5part, d2max, nullptr);
        density_merge_kernel<<<N / 256, 256, 0, stream>>>(top5part, noise, density);
        parent_partial_kernel<<<(N / TI) * JSPLIT, 256, 0, stream>>>(X, sq, density, minpart);
        score_merge_kernel<<<N / 256, 256, 0, stream>>>(minpart, density, d2max, score);
    }
    rank_kernel<<<N / 256, 256, 0, stream>>>(score, out);
}

// Round 4
// 1173.911 us; speedup vs baseline: 1.1836x; 1.1836x over previous
//
#include <hip/hip_runtime.h>
#include <math.h>

#define N 8192
#define C 128
#define NC 256
#define KNN 5

#define TI 64
#define TJ 64
#define JSPLIT 8
#define JTILES ((N / JSPLIT) / TJ)   // 16
#define LDSROW 68                    // floats per LDS row (GEMM staging pitch)
#define SQRT_C 11.313708498984761    // sqrt(128)
#define NTILE (N / 64)               // 128
#define NPAIR (NTILE * (NTILE + 1) / 2)   // 8256
#define TSP 65                       // Ts pitch in doubles

static __device__ __forceinline__ unsigned rotl32(unsigned x, unsigned r) {
    return (x << r) | (x >> (32u - r));
}

// order-preserving double -> uint64 map (ascending)
static __device__ __forceinline__ unsigned long long dmap(double x) {
    long long b = __double_as_longlong(x);
    unsigned long long u = (unsigned long long)b;
    return (b >= 0) ? (u | 0x8000000000000000ull) : ~u;
}
static __device__ __forceinline__ double dunmap(unsigned long long u) {
    if (u & 0x8000000000000000ull) return __longlong_as_double((long long)(u ^ 0x8000000000000000ull));
    return __longlong_as_double((long long)(~u));
}

// ---------------------------------------------------------------------------
__global__ void init_kernel(unsigned long long* d2max, unsigned long long* gmin) {
    int i = blockIdx.x * blockDim.x + threadIdx.x;
    if (i < N) gmin[i] = 0xFFFFFFFFFFFFFFFFull;
    if (i == 0) *d2max = 0ull;
}

// ---------------------------------------------------------------------------
// sq[i] = sum_c (double)x[i][c]^2
// ---------------------------------------------------------------------------
__global__ void sq_kernel(const float* __restrict__ X, double* __restrict__ sq) {
    int wave = (blockIdx.x * blockDim.x + threadIdx.x) >> 6;
    int lane = threadIdx.x & 63;
    if (wave >= N) return;
    double v0 = (double)X[wave * C + lane];
    double v1 = (double)X[wave * C + 64 + lane];
    double s = v0 * v0 + v1 * v1;
    #pragma unroll
    for (int off = 32; off > 0; off >>= 1) s += __shfl_down(s, off, 64);
    if (lane == 0) sq[wave] = s;
}

// ---------------------------------------------------------------------------
// JAX threefry2x32: uniform(key(1), (1,8192))
// ---------------------------------------------------------------------------
__global__ void noise_kernel(float* __restrict__ noise) {
    int j = blockIdx.x * blockDim.x + threadIdx.x;
    if (j >= N / 2) return;
    const unsigned ks0 = 0u, ks1 = 1u;
    const unsigned ks2 = 0x1BD11BDAu ^ ks0 ^ ks1;
    unsigned x0 = (unsigned)j + ks0;
    unsigned x1 = (unsigned)(j + N / 2) + ks1;
    const unsigned rotA[4] = {13u, 15u, 26u, 6u};
    const unsigned rotB[4] = {17u, 29u, 16u, 24u};
    #pragma unroll
    for (int r = 0; r < 4; r++) { x0 += x1; x1 = rotl32(x1, rotA[r]); x1 ^= x0; }
    x0 += ks1; x1 += ks2 + 1u;
    #pragma unroll
    for (int r = 0; r < 4; r++) { x0 += x1; x1 = rotl32(x1, rotB[r]); x1 ^= x0; }
    x0 += ks2; x1 += ks0 + 2u;
    #pragma unroll
    for (int r = 0; r < 4; r++) { x0 += x1; x1 = rotl32(x1, rotA[r]); x1 ^= x0; }
    x0 += ks0; x1 += ks1 + 3u;
    #pragma unroll
    for (int r = 0; r < 4; r++) { x0 += x1; x1 = rotl32(x1, rotB[r]); x1 ^= x0; }
    x0 += ks1; x1 += ks2 + 4u;
    #pragma unroll
    for (int r = 0; r < 4; r++) { x0 += x1; x1 = rotl32(x1, rotA[r]); x1 ^= x0; }
    x0 += ks2; x1 += ks0 + 5u;
    unsigned b0 = (x0 >> 9) | 0x3f800000u;
    unsigned b1 = (x1 >> 9) | 0x3f800000u;
    noise[j]         = __uint_as_float(b0) - 1.0f;
    noise[j + N / 2] = __uint_as_float(b1) - 1.0f;
}

// decode upper-tri pair index p -> (bi, bj), bi <= bj, column-major:
// p = bj*(bj+1)/2 + bi
static __device__ __forceinline__ void pair_decode(int p, int& bi, int& bj) {
    int b = (int)((sqrt(8.0 * (double)p + 1.0) - 1.0) * 0.5);
    while ((b + 1) * (b + 2) / 2 <= p) b++;
    while (b * (b + 1) / 2 > p) b--;
    bj = b;
    bi = p - b * (b + 1) / 2;
}

// ---------------------------------------------------------------------------
// Symmetric pass A: one block per upper-tri tile pair. GEMM 64x64x128 fp64,
// d2 tile -> LDS, wave0 row-scan (direct top5 + rowmax), wave1 col-scan
// (transposed top5, off-diagonal only). Records: rec_dir/rec_tr[p][64][5].
// ---------------------------------------------------------------------------
__launch_bounds__(256, 2)
__global__ void symA_kernel(const float* __restrict__ X,
                            const double* __restrict__ sq,
                            double* __restrict__ rec_dir,
                            double* __restrict__ rec_tr,
                            unsigned long long* __restrict__ d2max_p)
{
    __shared__ __align__(16) float S[2 * C * LDSROW];   // As|Bs, later reused as Ts
    float* As = S;
    float* Bs = S + C * LDSROW;

    const int t  = threadIdx.x;
    const int tx = t & 15;
    const int ty = t >> 4;
    int bi, bj;
    pair_decode(blockIdx.x, bi, bj);
    const int i0 = bi * 64, j0 = bj * 64;

    const float4* X4 = (const float4*)X;

    #pragma unroll
    for (int q = 0; q < 8; q++) {
        int flat = t + 256 * q;
        int row = flat >> 5, c4 = flat & 31;
        float4 va = X4[(size_t)(i0 + row) * 32 + c4];
        float4 vb = X4[(size_t)(j0 + row) * 32 + c4];
        float* da = &As[(4 * c4) * LDSROW + row];
        float* db = &Bs[(4 * c4) * LDSROW + row];
        da[0 * LDSROW] = va.x; da[1 * LDSROW] = va.y;
        da[2 * LDSROW] = va.z; da[3 * LDSROW] = va.w;
        db[0 * LDSROW] = vb.x; db[1 * LDSROW] = vb.y;
        db[2 * LDSROW] = vb.z; db[3 * LDSROW] = vb.w;
    }

    double sqa[4], sqj[4];
    #pragma unroll
    for (int r = 0; r < 4; r++) { sqa[r] = sq[i0 + 4 * ty + r]; sqj[r] = sq[j0 + 4 * tx + r]; }

    __syncthreads();

    double acc[4][4];
    #pragma unroll
    for (int r = 0; r < 4; r++)
        #pragma unroll
        for (int s = 0; s < 4; s++) acc[r][s] = 0.0;

    #pragma unroll 4
    for (int c = 0; c < C; c++) {
        float4 af = *(const float4*)&As[c * LDSROW + 4 * ty];
        float4 bf = *(const float4*)&Bs[c * LDSROW + 4 * tx];
        double a0 = af.x, a1 = af.y, a2 = af.z, a3 = af.w;
        double b0 = bf.x, b1 = bf.y, b2 = bf.z, b3 = bf.w;
        acc[0][0] += a0 * b0; acc[0][1] += a0 * b1; acc[0][2] += a0 * b2; acc[0][3] += a0 * b3;
        acc[1][0] += a1 * b0; acc[1][1] += a1 * b1; acc[1][2] += a1 * b2; acc[1][3] += a1 * b3;
        acc[2][0] += a2 * b0; acc[2][1] += a2 * b1; acc[2][2] += a2 * b2; acc[2][3] += a2 * b3;
        acc[3][0] += a3 * b0; acc[3][1] += a3 * b1; acc[3][2] += a3 * b2; acc[3][3] += a3 * b3;
    }

    __syncthreads();   // all LDS reads done; reuse S as Ts
    double* Ts = (double*)S;
    #pragma unroll
    for (int r = 0; r < 4; r++)
        #pragma unroll
        for (int s = 0; s < 4; s++)
            Ts[(4 * ty + r) * TSP + 4 * tx + s] = sqa[r] + sqj[s] - 2.0 * acc[r][s];
    __syncthreads();

    if (t < 64) {
        // direct: row t of tile bi over 64 cols of tile bj
        double m5[KNN];
        #pragma unroll
        for (int k = 0; k < KNN; k++) m5[k] = 1e300;
        double rmax = 0.0;
        for (int jj = 0; jj < 64; jj++) {
            double v = Ts[t * TSP + jj];
            rmax = fmax(rmax, v);
            if (v < m5[0]) {
                m5[0] = v;
                #pragma unroll
                for (int k = 1; k < KNN; k++)
                    if (m5[k] > m5[0]) { double tmp = m5[0]; m5[0] = m5[k]; m5[k] = tmp; }
            }
        }
        double* outp = &rec_dir[(size_t)blockIdx.x * 320 + t * KNN];
        #pragma unroll
        for (int k = 0; k < KNN; k++) outp[k] = m5[k];
        #pragma unroll
        for (int off = 32; off > 0; off >>= 1) rmax = fmax(rmax, __shfl_down(rmax, off, 64));
        if (t == 0) atomicMax(d2max_p, (unsigned long long)__double_as_longlong(rmax));
    } else if (t < 128 && bi != bj) {
        // transposed: col (t-64) of tile bj over 64 rows of tile bi
        int cc = t - 64;
        double m5[KNN];
        #pragma unroll
        for (int k = 0; k < KNN; k++) m5[k] = 1e300;
        for (int ii = 0; ii < 64; ii++) {
            double v = Ts[ii * TSP + cc];
            if (v < m5[0]) {
                m5[0] = v;
                #pragma unroll
                for (int k = 1; k < KNN; k++)
                    if (m5[k] > m5[0]) { double tmp = m5[0]; m5[0] = m5[k]; m5[k] = tmp; }
            }
        }
        double* outp = &rec_tr[(size_t)blockIdx.x * 320 + cc * KNN];
        #pragma unroll
        for (int k = 0; k < KNN; k++) outp[k] = m5[k];
    }
}

// ---------------------------------------------------------------------------
// Merge symA records -> density.  Row i: direct recs (bi=T, bj>=T) +
// transposed recs (pairs (bi<T, T)).  Exactly 128 records of 5.
// ---------------------------------------------------------------------------
__global__ void density_merge_sym_kernel(const double* __restrict__ rec_dir,
                                         const double* __restrict__ rec_tr,
                                         const float* __restrict__ noise,
                                         double* __restrict__ density)
{
    int i = blockIdx.x * blockDim.x + threadIdx.x;
    if (i >= N) return;
    int T = i >> 6, r = i & 63;
    double t5[KNN];
    #pragma unroll
    for (int k = 0; k < KNN; k++) t5[k] = 1e300;

    for (int bj = T; bj < NTILE; bj++) {
        int p = bj * (bj + 1) / 2 + T;
        const double* rp = &rec_dir[(size_t)p * 320 + r * KNN];
        #pragma unroll
        for (int k = 0; k < KNN; k++) {
            double v = rp[k];
            if (v < t5[0]) {
                t5[0] = v;
                #pragma unroll
                for (int q = 1; q < KNN; q++)
                    if (t5[q] > t5[0]) { double tmp = t5[0]; t5[0] = t5[q]; t5[q] = tmp; }
            }
        }
    }
    int cumT = T * (T + 1) / 2;
    for (int bi = 0; bi < T; bi++) {
        const double* rp = &rec_tr[(size_t)(cumT + bi) * 320 + r * KNN];
        #pragma unroll
        for (int k = 0; k < KNN; k++) {
            double v = rp[k];
            if (v < t5[0]) {
                t5[0] = v;
                #pragma unroll
                for (int q = 1; q < KNN; q++)
                    if (t5[q] > t5[0]) { double tmp = t5[0]; t5[0] = t5[q]; t5[q] = tmp; }
            }
        }
    }
    for (int a = 1; a < KNN; a++) {
        double key = t5[a]; int b = a - 1;
        while (b >= 0 && t5[b] > key) { t5[b + 1] = t5[b]; b--; }
        t5[b + 1] = key;
    }
    double s2 = 0.0;
    #pragma unroll
    for (int k = 0; k < KNN; k++) {
        double z = t5[k] > 0.0 ? t5[k] : 0.0;
        double d = sqrt(z) / SQRT_C;
        s2 += d * d;
    }
    density[i] = exp(-s2 / 5.0) + (double)(noise[i] * 1e-6f);
}

// ---------------------------------------------------------------------------
// Symmetric pass B: masked min both orientations, merged via atomicMin on
// order-preserved uint64.  No bulk workspace needed.
// ---------------------------------------------------------------------------
__launch_bounds__(256, 2)
__global__ void symB_kernel(const float* __restrict__ X,
                            const double* __restrict__ sq,
                            const double* __restrict__ density,
                            unsigned long long* __restrict__ gmin)
{
    __shared__ __align__(16) float S[2 * C * LDSROW];
    __shared__ double Drow[64], Dcol[64];
    float* As = S;
    float* Bs = S + C * LDSROW;

    const int t  = threadIdx.x;
    const int tx = t & 15;
    const int ty = t >> 4;
    int bi, bj;
    pair_decode(blockIdx.x, bi, bj);
    const int i0 = bi * 64, j0 = bj * 64;

    const float4* X4 = (const float4*)X;

    if (t < 64) Drow[t] = density[i0 + t];
    else if (t < 128) Dcol[t - 64] = density[j0 + t - 64];

    #pragma unroll
    for (int q = 0; q < 8; q++) {
        int flat = t + 256 * q;
        int row = flat >> 5, c4 = flat & 31;
        float4 va = X4[(size_t)(i0 + row) * 32 + c4];
        float4 vb = X4[(size_t)(j0 + row) * 32 + c4];
        float* da = &As[(4 * c4) * LDSROW + row];
        float* db = &Bs[(4 * c4) * LDSROW + row];
        da[0 * LDSROW] = va.x; da[1 * LDSROW] = va.y;
        da[2 * LDSROW] = va.z; da[3 * LDSROW] = va.w;
        db[0 * LDSROW] = vb.x; db[1 * LDSROW] = vb.y;
        db[2 * LDSROW] = vb.z; db[3 * LDSROW] = vb.w;
    }

    double sqa[4], sqj[4];
    #pragma unroll
    for (int r = 0; r < 4; r++) { sqa[r] = sq[i0 + 4 * ty + r]; sqj[r] = sq[j0 + 4 * tx + r]; }

    __syncthreads();

    double acc[4][4];
    #pragma unroll
    for (int r = 0; r < 4; r++)
        #pragma unroll
        for (int s = 0; s < 4; s++) acc[r][s] = 0.0;

    #pragma unroll 4
    for (int c = 0; c < C; c++) {
        float4 af = *(const float4*)&As[c * LDSROW + 4 * ty];
        float4 bf = *(const float4*)&Bs[c * LDSROW + 4 * tx];
        double a0 = af.x, a1 = af.y, a2 = af.z, a3 = af.w;
        double b0 = bf.x, b1 = bf.y, b2 = bf.z, b3 = bf.w;
        acc[0][0] += a0 * b0; acc[0][1] += a0 * b1; acc[0][2] += a0 * b2; acc[0][3] += a0 * b3;
        acc[1][0] += a1 * b0; acc[1][1] += a1 * b1; acc[1][2] += a1 * b2; acc[1][3] += a1 * b3;
        acc[2][0] += a2 * b0; acc[2][1] += a2 * b1; acc[2][2] += a2 * b2; acc[2][3] += a2 * b3;
        acc[3][0] += a3 * b0; acc[3][1] += a3 * b1; acc[3][2] += a3 * b2; acc[3][3] += a3 * b3;
    }

    __syncthreads();
    double* Ts = (double*)S;
    #pragma unroll
    for (int r = 0; r < 4; r++)
        #pragma unroll
        for (int s = 0; s < 4; s++)
            Ts[(4 * ty + r) * TSP + 4 * tx + s] = sqa[r] + sqj[s] - 2.0 * acc[r][s];
    __syncthreads();

    if (t < 64) {
        double di = Drow[t];
        double dmin = 1e300;
        for (int jj = 0; jj < 64; jj++) {
            double v = Ts[t * TSP + jj];
            if (Dcol[jj] > di) dmin = fmin(dmin, v);
        }
        if (dmin < 9.9e299) atomicMin(&gmin[i0 + t], dmap(dmin));
    } else if (t < 128 && bi != bj) {
        int cc = t - 64;
        double dj = Dcol[cc];
        double dmin = 1e300;
        for (int ii = 0; ii < 64; ii++) {
            double v = Ts[ii * TSP + cc];
            if (Drow[ii] > dj) dmin = fmin(dmin, v);
        }
        if (dmin < 9.9e299) atomicMin(&gmin[j0 + cc], dmap(dmin));
    }
}

// ---------------------------------------------------------------------------
__global__ void score_sym_kernel(const unsigned long long* __restrict__ gmin,
                                 const double* __restrict__ density,
                                 const unsigned long long* __restrict__ d2max_p,
                                 double* __restrict__ score)
{
    int i = blockIdx.x * blockDim.x + threadIdx.x;
    if (i >= N) return;
    unsigned long long u = gmin[i];
    double d2m = __longlong_as_double((long long)(*d2max_p));
    double distmax = sqrt(fmax(d2m, 0.0)) / SQRT_C;
    double dp;
    if (u == 0xFFFFFFFFFFFFFFFFull) {
        dp = distmax;
    } else {
        double dmin = dunmap(u);
        dp = sqrt(fmax(dmin, 0.0)) / SQRT_C;
    }
    score[i] = dp * density[i];
}

// ---------------------------------------------------------------------------
// Fallback pass A (R2, proven): full-matrix strips with in-register top-5.
// ---------------------------------------------------------------------------
__launch_bounds__(256, 2)
__global__ void density_partial_kernel(const float* __restrict__ X,
                                       const double* __restrict__ sq,
                                       double* __restrict__ top5part,
                                       unsigned long long* __restrict__ d2max_p)
{
    __shared__ __align__(16) float S[2 * C * LDSROW];
    __shared__ double Sqj[TJ];
    __shared__ double wmax[4];
    float* As = S;
    float* Bs = S + C * LDSROW;

    const int t  = threadIdx.x;
    const int tx = t & 15;
    const int ty = t >> 4;
    const int i0 = (blockIdx.x & 127) * TI;
    const int js = blockIdx.x >> 7;
    const int jbase = js * (N / JSPLIT);

    const float4* X4 = (const float4*)X;

    #pragma unroll
    for (int q = 0; q < 8; q++) {
        int flat = t + 256 * q;
        int row = flat >> 5, c4 = flat & 31;
        float4 v = X4[(size_t)(i0 + row) * 32 + c4];
        float* dst = &As[(4 * c4) * LDSROW + row];
        dst[0 * LDSROW] = v.x; dst[1 * LDSROW] = v.y;
        dst[2 * LDSROW] = v.z; dst[3 * LDSROW] = v.w;
    }

    double sqa[4];
    #pragma unroll
    for (int r = 0; r < 4; r++) sqa[r] = sq[i0 + 4 * ty + r];

    double t5[4][KNN];
    #pragma unroll
    for (int r = 0; r < 4; r++)
        #pragma unroll
        for (int k = 0; k < KNN; k++) t5[r][k] = 1e300;
    double rowmax = 0.0;

    for (int jt = 0; jt < JTILES; jt++) {
        int j0 = jbase + jt * TJ;
        __syncthreads();
        if (t < TJ) Sqj[t] = sq[j0 + t];
        #pragma unroll
        for (int q = 0; q < 8; q++) {
            int flat = t + 256 * q;
            int row = flat >> 5, c4 = flat & 31;
            float4 v = X4[(size_t)(j0 + row) * 32 + c4];
            float* dst = &Bs[(4 * c4) * LDSROW + row];
            dst[0 * LDSROW] = v.x; dst[1 * LDSROW] = v.y;
            dst[2 * LDSROW] = v.z; dst[3 * LDSROW] = v.w;
        }
        __syncthreads();

        double acc[4][4];
        #pragma unroll
        for (int r = 0; r < 4; r++)
            #pragma unroll
            for (int s = 0; s < 4; s++) acc[r][s] = 0.0;

        #pragma unroll 4
        for (int c = 0; c < C; c++) {
            float4 af = *(const float4*)&As[c * LDSROW + 4 * ty];
            float4 bf = *(const float4*)&Bs[c * LDSROW + 4 * tx];
            double a0 = af.x, a1 = af.y, a2 = af.z, a3 = af.w;
            double b0 = bf.x, b1 = bf.y, b2 = bf.z, b3 = bf.w;
            acc[0][0] += a0 * b0; acc[0][1] += a0 * b1; acc[0][2] += a0 * b2; acc[0][3] += a0 * b3;
            acc[1][0] += a1 * b0; acc[1][1] += a1 * b1; acc[1][2] += a1 * b2; acc[1][3] += a1 * b3;
            acc[2][0] += a2 * b0; acc[2][1] += a2 * b1; acc[2][2] += a2 * b2; acc[2][3] += a2 * b3;
            acc[3][0] += a3 * b0; acc[3][1] += a3 * b1; acc[3][2] += a3 * b2; acc[3][3] += a3 * b3;
        }

        #pragma unroll
        for (int r = 0; r < 4; r++) {
            #pragma unroll
            for (int s = 0; s < 4; s++) {
                double v = sqa[r] + Sqj[4 * tx + s] - 2.0 * acc[r][s];
                rowmax = fmax(rowmax, v);
                if (v < t5[r][0]) {
                    t5[r][0] = v;
                    #pragma unroll
                    for (int k = 1; k < KNN; k++)
                        if (t5[r][k] > t5[r][0]) { double tmp = t5[r][0]; t5[r][0] = t5[r][k]; t5[r][k] = tmp; }
                }
            }
        }
    }

    double tmax = rowmax;
    #pragma unroll
    for (int off = 32; off > 0; off >>= 1) tmax = fmax(tmax, __shfl_down(tmax, off, 64));
    if ((t & 63) == 0) wmax[t >> 6] = tmax;

    __syncthreads();

    double* M = (double*)S;
    #pragma unroll
    for (int r = 0; r < 4; r++)
        #pragma unroll
        for (int k = 0; k < KNN; k++)
            M[(4 * ty + r) * 80 + tx * KNN + k] = t5[r][k];
    __syncthreads();

    if (t == 0) {
        double bm = fmax(fmax(wmax[0], wmax[1]), fmax(wmax[2], wmax[3]));
        bm = fmax(bm, 0.0);
        atomicMax(d2max_p, (unsigned long long)__double_as_longlong(bm));
    }
    if (t < TI) {
        double m5[KNN];
        #pragma unroll
        for (int k = 0; k < KNN; k++) m5[k] = 1e300;
        const double* row = &M[t * 80];
        for (int q = 0; q < 80; q++) {
            double v = row[q];
            if (v < m5[0]) {
                m5[0] = v;
                #pragma unroll
                for (int k = 1; k < KNN; k++)
                    if (m5[k] > m5[0]) { double tmp = m5[0]; m5[0] = m5[k]; m5[k] = tmp; }
            }
        }
        double* outp = &top5part[((size_t)js * N + (i0 + t)) * KNN];
        #pragma unroll
        for (int k = 0; k < KNN; k++) outp[k] = m5[k];
    }
}

__global__ void density_merge_kernel(const double* __restrict__ top5part,
                                     const float* __restrict__ noise,
                                     double* __restrict__ density)
{
    int i = blockIdx.x * blockDim.x + threadIdx.x;
    if (i >= N) return;
    double t5[KNN];
    #pragma unroll
    for (int k = 0; k < KNN; k++) t5[k] = 1e300;
    for (int js = 0; js < JSPLIT; js++) {
        const double* p = &top5part[((size_t)js * N + i) * KNN];
        #pragma unroll
        for (int k = 0; k < KNN; k++) {
            double v = p[k];
            if (v < t5[0]) {
                t5[0] = v;
                #pragma unroll
                for (int q = 1; q < KNN; q++)
                    if (t5[q] > t5[0]) { double tmp = t5[0]; t5[0] = t5[q]; t5[q] = tmp; }
            }
        }
    }
    for (int a = 1; a < KNN; a++) {
        double key = t5[a]; int b = a - 1;
        while (b >= 0 && t5[b] > key) { t5[b + 1] = t5[b]; b--; }
        t5[b + 1] = key;
    }
    double s2 = 0.0;
    #pragma unroll
    for (int k = 0; k < KNN; k++) {
        double z = t5[k] > 0.0 ? t5[k] : 0.0;
        double d = sqrt(z) / SQRT_C;
        s2 += d * d;
    }
    density[i] = exp(-s2 / 5.0) + (double)(noise[i] * 1e-6f);
}

// ---------------------------------------------------------------------------
// Stable descending rank; out[rank] = i.
// ---------------------------------------------------------------------------
__launch_bounds__(256)
__global__ void rank_kernel(const double* __restrict__ score, int* __restrict__ out)
{
    __shared__ double Ss[N];
    #pragma unroll
    for (int k = 0; k < N / 256; k++) {
        int idx = threadIdx.x + 256 * k;
        Ss[idx] = score[idx];
    }
    __syncthreads();
    int i = blockIdx.x * 256 + threadIdx.x;
    double si = Ss[i];
    int rank = 0;
    for (int j = 0; j < N; j++) {
        double sj = Ss[j];
        rank += (sj > si) || (sj == si && j < i);
    }
    if (rank < NC) out[rank] = i;
}

// ---------------------------------------------------------------------------
extern "C" void kernel_launch(void* const* d_in, const int* in_sizes, int n_in,
                              void* d_out, int out_size, void* d_ws, size_t ws_size,
                              hipStream_t stream) {
    const float* X = (const float*)d_in[0];
    int* out = (int*)d_out;

    double* ws      = (double*)d_ws;
    double* sq      = ws;                      // 8192
    double* density = ws + 8192;               // 8192
    double* score   = ws + 16384;              // 8192
    unsigned long long* d2max = (unsigned long long*)(ws + 24576);
    unsigned long long* gmin  = (unsigned long long*)(ws + 24584);  // 8192
    float*  noise   = (float*)(ws + 32776);    // 8192 floats
    double* top5part = ws + 36872;             // fallback: 327680 dbl (~2.6MB)

    const size_t rec_bytes = (size_t)NPAIR * 64 * KNN * sizeof(double);  // 21.1 MB
    const size_t base_need = 4ull * 1024 * 1024;
    const bool   big = ws_size >= base_need + 2 * rec_bytes;             // ~46.5 MB
    double* rec_dir = (double*)((char*)d_ws + base_need);
    double* rec_tr  = (double*)((char*)d_ws + base_need + rec_bytes);

    init_kernel<<<N / 256, 256, 0, stream>>>(d2max, gmin);
    sq_kernel<<<N / 4, 256, 0, stream>>>(X, sq);
    noise_kernel<<<(N / 2) / 256, 256, 0, stream>>>(noise);

    if (big) {
        symA_kernel<<<NPAIR, 256, 0, stream>>>(X, sq, rec_dir, rec_tr, d2max);
        density_merge_sym_kernel<<<N / 256, 256, 0, stream>>>(rec_dir, rec_tr, noise, density);
    } else {
        density_partial_kernel<<<(N / TI) * JSPLIT, 256, 0, stream>>>(X, sq, top5part, d2max);
        density_merge_kernel<<<N / 256, 256, 0, stream>>>(top5part, noise, density);
    }
    symB_kernel<<<NPAIR, 256, 0, stream>>>(X, sq, density, gmin);
    score_sym_kernel<<<N / 256, 256, 0, stream>>>(gmin, density, d2max, score);
    rank_kernel<<<N / 256, 256, 0, stream>>>(score, out);
}

// Round 5
// 737.561 us; speedup vs baseline: 1.8838x; 1.5916x over previous
//
#include <hip/hip_runtime.h>
#include <math.h>

#define N 8192
#define C 128
#define NC 256
#define KNN 5

#define CH 64                        // channels per staging chunk
#define PITCH 68                     // floats per LDS staging row (16B-aligned)
#define TSP 65                       // Ts pitch in doubles (symA)
#define SQRT_C 11.313708498984761    // sqrt(128)
#define NTILE (N / 64)               // 128
#define NPAIR (NTILE * (NTILE + 1) / 2)   // 8256

static __device__ __forceinline__ unsigned rotl32(unsigned x, unsigned r) {
    return (x << r) | (x >> (32u - r));
}

// order-preserving double -> uint64 map (ascending)
static __device__ __forceinline__ unsigned long long dmap(double x) {
    long long b = __double_as_longlong(x);
    unsigned long long u = (unsigned long long)b;
    return (b >= 0) ? (u | 0x8000000000000000ull) : ~u;
}
static __device__ __forceinline__ double dunmap(unsigned long long u) {
    if (u & 0x8000000000000000ull) return __longlong_as_double((long long)(u ^ 0x8000000000000000ull));
    return __longlong_as_double((long long)(~u));
}

// keep 5 smallest; m5[0] holds current max of the 5
static __device__ __forceinline__ void ins5(double (&m5)[KNN], double v) {
    if (v < m5[0]) {
        m5[0] = v;
        #pragma unroll
        for (int k = 1; k < KNN; k++)
            if (m5[k] > m5[0]) { double tmp = m5[0]; m5[0] = m5[k]; m5[k] = tmp; }
    }
}

// ---------------------------------------------------------------------------
__global__ void init_kernel(unsigned long long* d2max, unsigned long long* gmin) {
    int i = blockIdx.x * blockDim.x + threadIdx.x;
    if (i < N) gmin[i] = 0xFFFFFFFFFFFFFFFFull;
    if (i == 0) *d2max = 0ull;
}

// ---------------------------------------------------------------------------
__global__ void sq_kernel(const float* __restrict__ X, double* __restrict__ sq) {
    int wave = (blockIdx.x * blockDim.x + threadIdx.x) >> 6;
    int lane = threadIdx.x & 63;
    if (wave >= N) return;
    double v0 = (double)X[wave * C + lane];
    double v1 = (double)X[wave * C + 64 + lane];
    double s = v0 * v0 + v1 * v1;
    #pragma unroll
    for (int off = 32; off > 0; off >>= 1) s += __shfl_down(s, off, 64);
    if (lane == 0) sq[wave] = s;
}

// ---------------------------------------------------------------------------
// JAX threefry2x32: uniform(key(1), (1,8192))
// ---------------------------------------------------------------------------
__global__ void noise_kernel(float* __restrict__ noise) {
    int j = blockIdx.x * blockDim.x + threadIdx.x;
    if (j >= N / 2) return;
    const unsigned ks0 = 0u, ks1 = 1u;
    const unsigned ks2 = 0x1BD11BDAu ^ ks0 ^ ks1;
    unsigned x0 = (unsigned)j + ks0;
    unsigned x1 = (unsigned)(j + N / 2) + ks1;
    const unsigned rotA[4] = {13u, 15u, 26u, 6u};
    const unsigned rotB[4] = {17u, 29u, 16u, 24u};
    #pragma unroll
    for (int r = 0; r < 4; r++) { x0 += x1; x1 = rotl32(x1, rotA[r]); x1 ^= x0; }
    x0 += ks1; x1 += ks2 + 1u;
    #pragma unroll
    for (int r = 0; r < 4; r++) { x0 += x1; x1 = rotl32(x1, rotB[r]); x1 ^= x0; }
    x0 += ks2; x1 += ks0 + 2u;
    #pragma unroll
    for (int r = 0; r < 4; r++) { x0 += x1; x1 = rotl32(x1, rotA[r]); x1 ^= x0; }
    x0 += ks0; x1 += ks1 + 3u;
    #pragma unroll
    for (int r = 0; r < 4; r++) { x0 += x1; x1 = rotl32(x1, rotB[r]); x1 ^= x0; }
    x0 += ks1; x1 += ks2 + 4u;
    #pragma unroll
    for (int r = 0; r < 4; r++) { x0 += x1; x1 = rotl32(x1, rotA[r]); x1 ^= x0; }
    x0 += ks2; x1 += ks0 + 5u;
    unsigned b0 = (x0 >> 9) | 0x3f800000u;
    unsigned b1 = (x1 >> 9) | 0x3f800000u;
    noise[j]         = __uint_as_float(b0) - 1.0f;
    noise[j + N / 2] = __uint_as_float(b1) - 1.0f;
}

// p = bj*(bj+1)/2 + bi, bi <= bj
static __device__ __forceinline__ void pair_decode(int p, int& bi, int& bj) {
    int b = (int)((sqrt(8.0 * (double)p + 1.0) - 1.0) * 0.5);
    while ((b + 1) * (b + 2) / 2 <= p) b++;
    while (b * (b + 1) / 2 > p) b--;
    bj = b;
    bi = p - b * (b + 1) / 2;
}

// ---------------------------------------------------------------------------
// symA: 64x64 tile-pair d2 GEMM (c-chunked staging, 4 blocks/CU) + 4-wave
// half-split top-5 scan.  Records rec_dir/rec_tr[p][64][5] + global d2max.
// ---------------------------------------------------------------------------
__launch_bounds__(256, 4)
__global__ void symA_kernel(const float* __restrict__ X,
                            const double* __restrict__ sq,
                            double* __restrict__ rec_dir,
                            double* __restrict__ rec_tr,
                            unsigned long long* __restrict__ d2max_p)
{
    __shared__ __align__(16) float S[2 * CH * PITCH];   // 34,816 B; reused as Ts
    __shared__ double H[2][64][KNN];                    // 5,120 B half-merge
    __shared__ double wmax[2];
    float* As = S;
    float* Bs = S + CH * PITCH;

    const int t  = threadIdx.x;
    const int tx = t & 15;
    const int ty = t >> 4;
    int bi, bj;
    pair_decode(blockIdx.x, bi, bj);
    const int i0 = bi * 64, j0 = bj * 64;
    const float4* X4 = (const float4*)X;

    // chunk0 loads (each thread: 4 float4 per side)
    float4 pa[4], pb[4];
    #pragma unroll
    for (int q = 0; q < 4; q++) {
        int flat = t + 256 * q, row = flat >> 4, c4 = flat & 15;
        pa[q] = X4[(size_t)(i0 + row) * 32 + c4];
        pb[q] = X4[(size_t)(j0 + row) * 32 + c4];
    }
    double sqa[4], sqj[4];
    #pragma unroll
    for (int r = 0; r < 4; r++) { sqa[r] = sq[i0 + 4 * ty + r]; sqj[r] = sq[j0 + 4 * tx + r]; }

    // store chunk0 transposed [c][i]
    #pragma unroll
    for (int q = 0; q < 4; q++) {
        int flat = t + 256 * q, row = flat >> 4, c4 = flat & 15;
        float* da = &As[(4 * c4) * PITCH + row];
        float* db = &Bs[(4 * c4) * PITCH + row];
        da[0 * PITCH] = pa[q].x; da[1 * PITCH] = pa[q].y; da[2 * PITCH] = pa[q].z; da[3 * PITCH] = pa[q].w;
        db[0 * PITCH] = pb[q].x; db[1 * PITCH] = pb[q].y; db[2 * PITCH] = pb[q].z; db[3 * PITCH] = pb[q].w;
    }
    __syncthreads();

    // prefetch chunk1 while computing chunk0
    #pragma unroll
    for (int q = 0; q < 4; q++) {
        int flat = t + 256 * q, row = flat >> 4, c4 = flat & 15;
        pa[q] = X4[(size_t)(i0 + row) * 32 + 16 + c4];
        pb[q] = X4[(size_t)(j0 + row) * 32 + 16 + c4];
    }

    double acc[4][4];
    #pragma unroll
    for (int r = 0; r < 4; r++)
        #pragma unroll
        for (int s = 0; s < 4; s++) acc[r][s] = 0.0;

    #pragma unroll 4
    for (int c = 0; c < CH; c++) {
        float4 af = *(const float4*)&As[c * PITCH + 4 * ty];
        float4 bf = *(const float4*)&Bs[c * PITCH + 4 * tx];
        double a0 = af.x, a1 = af.y, a2 = af.z, a3 = af.w;
        double b0 = bf.x, b1 = bf.y, b2 = bf.z, b3 = bf.w;
        acc[0][0] += a0 * b0; acc[0][1] += a0 * b1; acc[0][2] += a0 * b2; acc[0][3] += a0 * b3;
        acc[1][0] += a1 * b0; acc[1][1] += a1 * b1; acc[1][2] += a1 * b2; acc[1][3] += a1 * b3;
        acc[2][0] += a2 * b0; acc[2][1] += a2 * b1; acc[2][2] += a2 * b2; acc[2][3] += a2 * b3;
        acc[3][0] += a3 * b0; acc[3][1] += a3 * b1; acc[3][2] += a3 * b2; acc[3][3] += a3 * b3;
    }
    __syncthreads();

    // store chunk1
    #pragma unroll
    for (int q = 0; q < 4; q++) {
        int flat = t + 256 * q, row = flat >> 4, c4 = flat & 15;
        float* da = &As[(4 * c4) * PITCH + row];
        float* db = &Bs[(4 * c4) * PITCH + row];
        da[0 * PITCH] = pa[q].x; da[1 * PITCH] = pa[q].y; da[2 * PITCH] = pa[q].z; da[3 * PITCH] = pa[q].w;
        db[0 * PITCH] = pb[q].x; db[1 * PITCH] = pb[q].y; db[2 * PITCH] = pb[q].z; db[3 * PITCH] = pb[q].w;
    }
    __syncthreads();

    #pragma unroll 4
    for (int c = 0; c < CH; c++) {
        float4 af = *(const float4*)&As[c * PITCH + 4 * ty];
        float4 bf = *(const float4*)&Bs[c * PITCH + 4 * tx];
        double a0 = af.x, a1 = af.y, a2 = af.z, a3 = af.w;
        double b0 = bf.x, b1 = bf.y, b2 = bf.z, b3 = bf.w;
        acc[0][0] += a0 * b0; acc[0][1] += a0 * b1; acc[0][2] += a0 * b2; acc[0][3] += a0 * b3;
        acc[1][0] += a1 * b0; acc[1][1] += a1 * b1; acc[1][2] += a1 * b2; acc[1][3] += a1 * b3;
        acc[2][0] += a2 * b0; acc[2][1] += a2 * b1; acc[2][2] += a2 * b2; acc[2][3] += a2 * b3;
        acc[3][0] += a3 * b0; acc[3][1] += a3 * b1; acc[3][2] += a3 * b2; acc[3][3] += a3 * b3;
    }
    __syncthreads();   // staging dead; reuse as Ts

    double* Ts = (double*)S;   // [64][TSP]
    #pragma unroll
    for (int r = 0; r < 4; r++)
        #pragma unroll
        for (int s = 0; s < 4; s++)
            Ts[(4 * ty + r) * TSP + 4 * tx + s] = sqa[r] + sqj[s] - 2.0 * acc[r][s];
    __syncthreads();

    // 4-wave half-split scan: waves 0,1 rows (halves), waves 2,3 cols (halves)
    double m5[KNN];
    #pragma unroll
    for (int k = 0; k < KNN; k++) m5[k] = 1e300;
    double rmax = 0.0;
    const int side = t >> 7, h = (t >> 6) & 1, ln = t & 63;
    if (side == 0) {
        const double* rowp = &Ts[ln * TSP + 32 * h];
        for (int jj = 0; jj < 32; jj++) {
            double v = rowp[jj];
            rmax = fmax(rmax, v);
            ins5(m5, v);
        }
    } else if (bi != bj) {
        for (int ii = 0; ii < 32; ii++) ins5(m5, Ts[(32 * h + ii) * TSP + ln]);
    }
    double wm = rmax;
    #pragma unroll
    for (int off = 32; off > 0; off >>= 1) wm = fmax(wm, __shfl_down(wm, off, 64));
    if ((t & 63) == 0 && side == 0) wmax[h] = wm;
    if (h == 1) {
        #pragma unroll
        for (int k = 0; k < KNN; k++) H[side][ln][k] = m5[k];
    }
    __syncthreads();
    if (h == 0) {
        #pragma unroll
        for (int k = 0; k < KNN; k++) ins5(m5, H[side][ln][k]);
        if (side == 0) {
            double* outp = &rec_dir[(size_t)blockIdx.x * 320 + ln * KNN];
            #pragma unroll
            for (int k = 0; k < KNN; k++) outp[k] = m5[k];
        } else if (bi != bj) {
            double* outp = &rec_tr[(size_t)blockIdx.x * 320 + ln * KNN];
            #pragma unroll
            for (int k = 0; k < KNN; k++) outp[k] = m5[k];
        }
    }
    if (t == 0)
        atomicMax(d2max_p, (unsigned long long)__double_as_longlong(
            fmax(fmax(wmax[0], wmax[1]), 0.0)));
}

// ---------------------------------------------------------------------------
// Merge symA records -> density (identical semantics to R4, proven).
// ---------------------------------------------------------------------------
__global__ void density_merge_sym_kernel(const double* __restrict__ rec_dir,
                                         const double* __restrict__ rec_tr,
                                         const float* __restrict__ noise,
                                         double* __restrict__ density)
{
    int i = blockIdx.x * blockDim.x + threadIdx.x;
    if (i >= N) return;
    int T = i >> 6, r = i & 63;
    double t5[KNN];
    #pragma unroll
    for (int k = 0; k < KNN; k++) t5[k] = 1e300;

    for (int bj = T; bj < NTILE; bj++) {
        int p = bj * (bj + 1) / 2 + T;
        const double* rp = &rec_dir[(size_t)p * 320 + r * KNN];
        #pragma unroll
        for (int k = 0; k < KNN; k++) ins5(t5, rp[k]);
    }
    int cumT = T * (T + 1) / 2;
    for (int bi = 0; bi < T; bi++) {
        const double* rp = &rec_tr[(size_t)(cumT + bi) * 320 + r * KNN];
        #pragma unroll
        for (int k = 0; k < KNN; k++) ins5(t5, rp[k]);
    }
    for (int a = 1; a < KNN; a++) {
        double key = t5[a]; int b = a - 1;
        while (b >= 0 && t5[b] > key) { t5[b + 1] = t5[b]; b--; }
        t5[b + 1] = key;
    }
    double s2 = 0.0;
    #pragma unroll
    for (int k = 0; k < KNN; k++) {
        double z = t5[k] > 0.0 ? t5[k] : 0.0;
        double d = sqrt(z) / SQRT_C;
        s2 += d * d;
    }
    density[i] = exp(-s2 / 5.0) + (double)(noise[i] * 1e-6f);
}

// ---------------------------------------------------------------------------
// symB: same GEMM; masked min folded into register epilogue (no Ts).
// Merge via LDS (pitch 17) then atomicMin on mapped uint64.
// ---------------------------------------------------------------------------
__launch_bounds__(256, 4)
__global__ void symB_kernel(const float* __restrict__ X,
                            const double* __restrict__ sq,
                            const double* __restrict__ density,
                            unsigned long long* __restrict__ gmin)
{
    __shared__ __align__(16) float S[2 * CH * PITCH];   // reused as Mr/Mc
    __shared__ double Drow[64], Dcol[64];
    float* As = S;
    float* Bs = S + CH * PITCH;

    const int t  = threadIdx.x;
    const int tx = t & 15;
    const int ty = t >> 4;
    int bi, bj;
    pair_decode(blockIdx.x, bi, bj);
    const int i0 = bi * 64, j0 = bj * 64;
    const float4* X4 = (const float4*)X;

    if (t < 64) Drow[t] = density[i0 + t];
    else if (t < 128) Dcol[t - 64] = density[j0 + t - 64];

    float4 pa[4], pb[4];
    #pragma unroll
    for (int q = 0; q < 4; q++) {
        int flat = t + 256 * q, row = flat >> 4, c4 = flat & 15;
        pa[q] = X4[(size_t)(i0 + row) * 32 + c4];
        pb[q] = X4[(size_t)(j0 + row) * 32 + c4];
    }
    double sqa[4], sqj[4];
    #pragma unroll
    for (int r = 0; r < 4; r++) { sqa[r] = sq[i0 + 4 * ty + r]; sqj[r] = sq[j0 + 4 * tx + r]; }

    #pragma unroll
    for (int q = 0; q < 4; q++) {
        int flat = t + 256 * q, row = flat >> 4, c4 = flat & 15;
        float* da = &As[(4 * c4) * PITCH + row];
        float* db = &Bs[(4 * c4) * PITCH + row];
        da[0 * PITCH] = pa[q].x; da[1 * PITCH] = pa[q].y; da[2 * PITCH] = pa[q].z; da[3 * PITCH] = pa[q].w;
        db[0 * PITCH] = pb[q].x; db[1 * PITCH] = pb[q].y; db[2 * PITCH] = pb[q].z; db[3 * PITCH] = pb[q].w;
    }
    __syncthreads();

    #pragma unroll
    for (int q = 0; q < 4; q++) {
        int flat = t + 256 * q, row = flat >> 4, c4 = flat & 15;
        pa[q] = X4[(size_t)(i0 + row) * 32 + 16 + c4];
        pb[q] = X4[(size_t)(j0 + row) * 32 + 16 + c4];
    }

    double acc[4][4];
    #pragma unroll
    for (int r = 0; r < 4; r++)
        #pragma unroll
        for (int s = 0; s < 4; s++) acc[r][s] = 0.0;

    #pragma unroll 4
    for (int c = 0; c < CH; c++) {
        float4 af = *(const float4*)&As[c * PITCH + 4 * ty];
        float4 bf = *(const float4*)&Bs[c * PITCH + 4 * tx];
        double a0 = af.x, a1 = af.y, a2 = af.z, a3 = af.w;
        double b0 = bf.x, b1 = bf.y, b2 = bf.z, b3 = bf.w;
        acc[0][0] += a0 * b0; acc[0][1] += a0 * b1; acc[0][2] += a0 * b2; acc[0][3] += a0 * b3;
        acc[1][0] += a1 * b0; acc[1][1] += a1 * b1; acc[1][2] += a1 * b2; acc[1][3] += a1 * b3;
        acc[2][0] += a2 * b0; acc[2][1] += a2 * b1; acc[2][2] += a2 * b2; acc[2][3] += a2 * b3;
        acc[3][0] += a3 * b0; acc[3][1] += a3 * b1; acc[3][2] += a3 * b2; acc[3][3] += a3 * b3;
    }
    __syncthreads();

    #pragma unroll
    for (int q = 0; q < 4; q++) {
        int flat = t + 256 * q, row = flat >> 4, c4 = flat & 15;
        float* da = &As[(4 * c4) * PITCH + row];
        float* db = &Bs[(4 * c4) * PITCH + row];
        da[0 * PITCH] = pa[q].x; da[1 * PITCH] = pa[q].y; da[2 * PITCH] = pa[q].z; da[3 * PITCH] = pa[q].w;
        db[0 * PITCH] = pb[q].x; db[1 * PITCH] = pb[q].y; db[2 * PITCH] = pb[q].z; db[3 * PITCH] = pb[q].w;
    }
    __syncthreads();

    #pragma unroll 4
    for (int c = 0; c < CH; c++) {
        float4 af = *(const float4*)&As[c * PITCH + 4 * ty];
        float4 bf = *(const float4*)&Bs[c * PITCH + 4 * tx];
        double a0 = af.x, a1 = af.y, a2 = af.z, a3 = af.w;
        double b0 = bf.x, b1 = bf.y, b2 = bf.z, b3 = bf.w;
        acc[0][0] += a0 * b0; acc[0][1] += a0 * b1; acc[0][2] += a0 * b2; acc[0][3] += a0 * b3;
        acc[1][0] += a1 * b0; acc[1][1] += a1 * b1; acc[1][2] += a1 * b2; acc[1][3] += a1 * b3;
        acc[2][0] += a2 * b0; acc[2][1] += a2 * b1; acc[2][2] += a2 * b2; acc[2][3] += a2 * b3;
        acc[3][0] += a3 * b0; acc[3][1] += a3 * b1; acc[3][2] += a3 * b2; acc[3][3] += a3 * b3;
    }

    // register epilogue: masked row/col mins
    double di[4], dj[4], dmr[4], dmc[4];
    #pragma unroll
    for (int r = 0; r < 4; r++) { di[r] = Drow[4 * ty + r]; dmr[r] = 1e300; }
    #pragma unroll
    for (int s = 0; s < 4; s++) { dj[s] = Dcol[4 * tx + s]; dmc[s] = 1e300; }
    #pragma unroll
    for (int r = 0; r < 4; r++)
        #pragma unroll
        for (int s = 0; s < 4; s++) {
            double v = sqa[r] + sqj[s] - 2.0 * acc[r][s];
            if (dj[s] > di[r]) dmr[r] = fmin(dmr[r], v);
            if (di[r] > dj[s]) dmc[s] = fmin(dmc[s], v);
        }

    __syncthreads();   // staging dead; reuse as Mr/Mc
    double* Mr = (double*)S;            // [64][17]
    double* Mc = Mr + 64 * 17;          // [64][17]
    #pragma unroll
    for (int r = 0; r < 4; r++) Mr[(4 * ty + r) * 17 + tx] = dmr[r];
    #pragma unroll
    for (int s = 0; s < 4; s++) Mc[(4 * tx + s) * 17 + ty] = dmc[s];
    __syncthreads();

    if (t < 64) {
        double m = 1e300;
        const double* row = &Mr[t * 17];
        #pragma unroll
        for (int q = 0; q < 16; q++) m = fmin(m, row[q]);
        if (m < 9.9e299) atomicMin(&gmin[i0 + t], dmap(m));
    } else if (t < 128 && bi != bj) {
        int c = t - 64;
        double m = 1e300;
        const double* row = &Mc[c * 17];
        #pragma unroll
        for (int q = 0; q < 16; q++) m = fmin(m, row[q]);
        if (m < 9.9e299) atomicMin(&gmin[j0 + c], dmap(m));
    }
}

// ---------------------------------------------------------------------------
__global__ void score_sym_kernel(const unsigned long long* __restrict__ gmin,
                                 const double* __restrict__ density,
                                 const unsigned long long* __restrict__ d2max_p,
                                 double* __restrict__ score)
{
    int i = blockIdx.x * blockDim.x + threadIdx.x;
    if (i >= N) return;
    unsigned long long u = gmin[i];
    double d2m = __longlong_as_double((long long)(*d2max_p));
    double distmax = sqrt(fmax(d2m, 0.0)) / SQRT_C;
    double dp;
    if (u == 0xFFFFFFFFFFFFFFFFull) {
        dp = distmax;
    } else {
        double dmin = dunmap(u);
        dp = sqrt(fmax(dmin, 0.0)) / SQRT_C;
    }
    score[i] = dp * density[i];
}

// ---------------------------------------------------------------------------
// Stable descending rank; 256 blocks, 8-way j-split per row, shuffle reduce.
// ---------------------------------------------------------------------------
__launch_bounds__(256)
__global__ void rank_kernel(const double* __restrict__ score, int* __restrict__ out)
{
    __shared__ double Ss[N];   // 64 KB
    for (int k = 0; k < N / 256; k++) {
        int idx = threadIdx.x + 256 * k;
        Ss[idx] = score[idx];
    }
    __syncthreads();
    int il = threadIdx.x >> 3;          // 0..31
    int ch = threadIdx.x & 7;           // 0..7
    int i = blockIdx.x * 32 + il;
    double si = Ss[i];
    int cnt = 0;
    for (int q = 0; q < N / 8; q++) {
        int j = ch + (q << 3);
        double sj = Ss[j];
        cnt += (sj > si) || (sj == si && j < i);
    }
    cnt += __shfl_down(cnt, 4, 8);
    cnt += __shfl_down(cnt, 2, 8);
    cnt += __shfl_down(cnt, 1, 8);
    if (ch == 0 && cnt < NC) out[cnt] = i;
}

// ---------------------------------------------------------------------------
extern "C" void kernel_launch(void* const* d_in, const int* in_sizes, int n_in,
                              void* d_out, int out_size, void* d_ws, size_t ws_size,
                              hipStream_t stream) {
    const float* X = (const float*)d_in[0];
    int* out = (int*)d_out;

    double* ws      = (double*)d_ws;
    double* sq      = ws;                      // 8192
    double* density = ws + 8192;               // 8192
    double* score   = ws + 16384;              // 8192
    unsigned long long* d2max = (unsigned long long*)(ws + 24576);
    unsigned long long* gmin  = (unsigned long long*)(ws + 24584);  // 8192
    float*  noise   = (float*)(ws + 32776);    // 8192 floats

    const size_t rec_bytes = (size_t)NPAIR * 64 * KNN * sizeof(double);  // 21.1 MB
    const size_t base_need = 4ull * 1024 * 1024;
    // R4 confirmed ws_size >= base_need + 2*rec_bytes (records were written).
    double* rec_dir = (double*)((char*)d_ws + base_need);
    double* rec_tr  = (double*)((char*)d_ws + base_need + rec_bytes);

    init_kernel<<<N / 256, 256, 0, stream>>>(d2max, gmin);
    sq_kernel<<<N / 4, 256, 0, stream>>>(X, sq);
    noise_kernel<<<(N / 2) / 256, 256, 0, stream>>>(noise);

    symA_kernel<<<NPAIR, 256, 0, stream>>>(X, sq, rec_dir, rec_tr, d2max);
    density_merge_sym_kernel<<<N / 256, 256, 0, stream>>>(rec_dir, rec_tr, noise, density);
    symB_kernel<<<NPAIR, 256, 0, stream>>>(X, sq, density, gmin);
    score_sym_kernel<<<N / 256, 256, 0, stream>>>(gmin, density, d2max, score);
    rank_kernel<<<N / 32, 256, 0, stream>>>(score, out);
}